// Round 1
// baseline (862.964 us; speedup 1.0000x reference)
//
#include <hip/hip_runtime.h>

// GCN 2-layer + edge dot decoder.
// Dims fixed by reference: in=512, hid=128, out=64.
#define IN_C  512
#define HID_C 128
#define OUT_C 64

// ---------------- degree / dinv ----------------
__global__ void k_init_deg(float* __restrict__ deg, int n) {
    int i = blockIdx.x * blockDim.x + threadIdx.x;
    if (i < n) deg[i] = 1.0f;  // self-loop
}

__global__ void k_count_deg(const int* __restrict__ dst, float* __restrict__ deg, int e) {
    int i = blockIdx.x * blockDim.x + threadIdx.x;
    if (i < e) atomicAdd(&deg[dst[i]], 1.0f);
}

__global__ void k_rsqrt(const float* __restrict__ deg, float* __restrict__ dinv, int n) {
    int i = blockIdx.x * blockDim.x + threadIdx.x;
    if (i < n) dinv[i] = rsqrtf(deg[i]);
}

// ---------------- GEMM: C = (A @ B) * dinv[row], written to Hs AND Agg ----------------
// N (cols) == BN exactly; grid.x tiles rows. A: [M,K] row-major, B: [K,BN] row-major.
template <int BM, int BN, int BK, int TM, int TN>
__global__ __launch_bounds__((BM / TM) * (BN / TN)) void k_gemm_scale(
    const float* __restrict__ A, const float* __restrict__ B,
    const float* __restrict__ dinv, float* __restrict__ Hs, float* __restrict__ Agg,
    int M, int K) {
    constexpr int NTH = (BM / TM) * (BN / TN);
    __shared__ float As[BK][BM];  // transposed A tile
    __shared__ float Bs[BK][BN];

    const int tid = threadIdx.x;
    const int m0 = blockIdx.x * BM;
    const int col_g = tid % (BN / TN);
    const int row_g = tid / (BN / TN);

    float acc[TM][TN];
#pragma unroll
    for (int i = 0; i < TM; ++i)
#pragma unroll
        for (int j = 0; j < TN; ++j) acc[i][j] = 0.0f;

    for (int k0 = 0; k0 < K; k0 += BK) {
        // A tile: BM x BK, float4 over K, store transposed
#pragma unroll
        for (int idx = tid; idx < BM * BK / 4; idx += NTH) {
            int row = idx / (BK / 4);
            int kq = idx % (BK / 4);
            int gm = m0 + row;
            float4 v = make_float4(0.f, 0.f, 0.f, 0.f);
            if (gm < M) v = *(const float4*)&A[(long)gm * K + k0 + kq * 4];
            As[kq * 4 + 0][row] = v.x;
            As[kq * 4 + 1][row] = v.y;
            As[kq * 4 + 2][row] = v.z;
            As[kq * 4 + 3][row] = v.w;
        }
        // B tile: BK x BN (K,BN multiples of BK/4 — no guard needed)
#pragma unroll
        for (int idx = tid; idx < BK * BN / 4; idx += NTH) {
            int row = idx / (BN / 4);
            int cq = idx % (BN / 4);
            *(float4*)&Bs[row][cq * 4] = *(const float4*)&B[(long)(k0 + row) * BN + cq * 4];
        }
        __syncthreads();

#pragma unroll
        for (int k = 0; k < BK; ++k) {
            float a[TM], b[TN];
            const float4* ap = (const float4*)&As[k][row_g * TM];
#pragma unroll
            for (int i = 0; i < TM / 4; ++i) {
                float4 av = ap[i];
                a[i * 4 + 0] = av.x; a[i * 4 + 1] = av.y;
                a[i * 4 + 2] = av.z; a[i * 4 + 3] = av.w;
            }
            const float4* bp = (const float4*)&Bs[k][col_g * TN];
#pragma unroll
            for (int j = 0; j < TN / 4; ++j) {
                float4 bv = bp[j];
                b[j * 4 + 0] = bv.x; b[j * 4 + 1] = bv.y;
                b[j * 4 + 2] = bv.z; b[j * 4 + 3] = bv.w;
            }
#pragma unroll
            for (int i = 0; i < TM; ++i)
#pragma unroll
                for (int j = 0; j < TN; ++j) acc[i][j] = fmaf(a[i], b[j], acc[i][j]);
        }
        __syncthreads();
    }

    // epilogue: scale by dinv[row], write to Hs and Agg (Agg init = self-loop term)
#pragma unroll
    for (int i = 0; i < TM; ++i) {
        int gm = m0 + row_g * TM + i;
        if (gm >= M) break;
        float dv = dinv[gm];
#pragma unroll
        for (int j = 0; j < TN / 4; ++j) {
            float4 v;
            v.x = acc[i][j * 4 + 0] * dv;
            v.y = acc[i][j * 4 + 1] * dv;
            v.z = acc[i][j * 4 + 2] * dv;
            v.w = acc[i][j * 4 + 3] * dv;
            long off = (long)gm * BN + col_g * TN + j * 4;
            *(float4*)&Hs[off] = v;
            *(float4*)&Agg[off] = v;
        }
    }
}

// ---------------- scatter-add: Agg[dst] += Hs[src], per (edge,channel) ----------------
template <int CLOG>
__global__ void k_scatter(const float* __restrict__ Hs, const int* __restrict__ src,
                          const int* __restrict__ dst, float* __restrict__ Agg,
                          unsigned total) {
    unsigned gid = blockIdx.x * blockDim.x + threadIdx.x;
    if (gid >= total) return;
    unsigned e = gid >> CLOG;
    unsigned c = gid & ((1u << CLOG) - 1u);
    int s = src[e], d = dst[e];
    atomicAdd(&Agg[((long)d << CLOG) + c], Hs[((long)s << CLOG) + c]);
}

// ---------------- epilogue: z = (maybe relu)(agg * dinv[node] + bias) in-place ----------------
template <int CLOG, bool RELU>
__global__ void k_epi(float* __restrict__ agg, const float* __restrict__ dinv,
                      const float* __restrict__ bias, int total4) {
    int i = blockIdx.x * blockDim.x + threadIdx.x;
    if (i >= total4) return;
    int base = i * 4;
    int node = base >> CLOG;
    int c = base & ((1 << CLOG) - 1);
    float dv = dinv[node];
    float4 v = *(float4*)&agg[base];
    float4 b = *(const float4*)&bias[c];
    v.x = fmaf(v.x, dv, b.x);
    v.y = fmaf(v.y, dv, b.y);
    v.z = fmaf(v.z, dv, b.z);
    v.w = fmaf(v.w, dv, b.w);
    if (RELU) {
        v.x = fmaxf(v.x, 0.f);
        v.y = fmaxf(v.y, 0.f);
        v.z = fmaxf(v.z, 0.f);
        v.w = fmaxf(v.w, 0.f);
    }
    *(float4*)&agg[base] = v;
}

// ---------------- decoder: out[l] = dot(z2[es[l]], z2[ed[l]]) over 64 channels ----------------
__global__ void k_dot(const float* __restrict__ z2, const int* __restrict__ es,
                      const int* __restrict__ ed, float* __restrict__ out, int L) {
    int gid = blockIdx.x * blockDim.x + threadIdx.x;
    int wid = gid >> 6;
    int lane = threadIdx.x & 63;
    if (wid >= L) return;
    int a = es[wid], b = ed[wid];
    float v = z2[(long)a * OUT_C + lane] * z2[(long)b * OUT_C + lane];
#pragma unroll
    for (int off = 32; off > 0; off >>= 1) v += __shfl_down(v, off);
    if (lane == 0) out[wid] = v;
}

extern "C" void kernel_launch(void* const* d_in, const int* in_sizes, int n_in,
                              void* d_out, int out_size, void* d_ws, size_t ws_size,
                              hipStream_t stream) {
    const float* x = (const float*)d_in[0];
    const int* ei = (const int*)d_in[1];
    const int* eli = (const int*)d_in[2];
    const float* W1 = (const float*)d_in[3];
    const float* b1 = (const float*)d_in[4];
    const float* W2 = (const float*)d_in[5];
    const float* b2 = (const float*)d_in[6];
    float* out = (float*)d_out;

    const int N = in_sizes[0] / IN_C;   // 50000
    const int E = in_sizes[1] / 2;      // 800000
    const int L = in_sizes[2] / 2;      // 100000
    const int* src = ei;
    const int* dst = ei + E;
    const int* es = eli;
    const int* ed = eli + L;

    // workspace layout (floats); total ~77.2 MB
    const int Npad = (N + 63) & ~63;
    float* ws = (float*)d_ws;
    float* deg = ws;                    // Npad
    float* dinv = deg + Npad;           // Npad
    float* h1s = dinv + Npad;           // N*128  (h1 * dinv[row])
    float* agg1 = h1s + (long)N * HID_C;  // N*128  (becomes z1 in-place)
    float* h2s = agg1 + (long)N * HID_C;  // N*64
    float* agg2 = h2s + (long)N * OUT_C;  // N*64   (becomes z2 in-place)

    const int TPB = 256;

    // 1-3: degree + dinv
    k_init_deg<<<(N + TPB - 1) / TPB, TPB, 0, stream>>>(deg, N);
    k_count_deg<<<(E + TPB - 1) / TPB, TPB, 0, stream>>>(dst, deg, E);
    k_rsqrt<<<(N + TPB - 1) / TPB, TPB, 0, stream>>>(deg, dinv, N);

    // 4: h1s = agg1 = (x @ W1) * dinv[row]
    k_gemm_scale<64, HID_C, 32, 8, 4>
        <<<(N + 63) / 64, 256, 0, stream>>>(x, W1, dinv, h1s, agg1, N, IN_C);

    // 5: scatter layer 1
    {
        unsigned total = (unsigned)E * HID_C;
        k_scatter<7><<<(total + TPB - 1) / TPB, TPB, 0, stream>>>(h1s, src, dst, agg1, total);
    }
    // 6: z1 = relu(agg1 * dinv + b1), in-place
    k_epi<7, true><<<((N * HID_C / 4) + TPB - 1) / TPB, TPB, 0, stream>>>(
        agg1, dinv, b1, N * HID_C / 4);

    // 7: h2s = agg2 = (z1 @ W2) * dinv[row]
    k_gemm_scale<128, OUT_C, 32, 8, 4>
        <<<(N + 127) / 128, 256, 0, stream>>>(agg1, W2, dinv, h2s, agg2, N, HID_C);

    // 8: scatter layer 2
    {
        unsigned total = (unsigned)E * OUT_C;
        k_scatter<6><<<(total + TPB - 1) / TPB, TPB, 0, stream>>>(h2s, src, dst, agg2, total);
    }
    // 9: z2 = agg2 * dinv + b2, in-place (no relu)
    k_epi<6, false><<<((N * OUT_C / 4) + TPB - 1) / TPB, TPB, 0, stream>>>(
        agg2, dinv, b2, N * OUT_C / 4);

    // 10: decoder
    k_dot<<<((long)L * 64 + TPB - 1) / TPB, TPB, 0, stream>>>(agg2, es, ed, out, L);
}

// Round 2
// 483.304 us; speedup vs baseline: 1.7856x; 1.7856x over previous
//
#include <hip/hip_runtime.h>

// GCN 2-layer + edge dot decoder. Dims fixed: in=512, hid=128, out=64.
#define IN_C  512
#define HID_C 128
#define OUT_C 64

// ---------------- CSR build ----------------
__global__ void k_zero_int(int* __restrict__ p, int n) {
    int i = blockIdx.x * blockDim.x + threadIdx.x;
    if (i < n) p[i] = 0;
}

__global__ void k_count(const int* __restrict__ dst, int* __restrict__ cnt, int e) {
    int i = blockIdx.x * blockDim.x + threadIdx.x;
    if (i < e) atomicAdd(&cnt[dst[i]], 1);
}

__global__ void k_dinv(const int* __restrict__ cnt, float* __restrict__ dinv, int n) {
    int i = blockIdx.x * blockDim.x + threadIdx.x;
    if (i < n) dinv[i] = rsqrtf(1.0f + (float)cnt[i]);  // +1 self-loop
}

// block sums of cnt (256 elems/block)
__global__ void k_blocksum(const int* __restrict__ cnt, int* __restrict__ bsum, int n) {
    __shared__ int sdata[256];
    int t = threadIdx.x;
    int i = blockIdx.x * 256 + t;
    sdata[t] = (i < n) ? cnt[i] : 0;
    __syncthreads();
    for (int s = 128; s > 0; s >>= 1) {
        if (t < s) sdata[t] += sdata[t + s];
        __syncthreads();
    }
    if (t == 0) bsum[blockIdx.x] = sdata[0];
}

// single-block exclusive scan of bsum (nb <= 256)
__global__ void k_scanpartials(int* __restrict__ bsum, int nb) {
    __shared__ int sdata[256];
    int t = threadIdx.x;
    int orig = (t < nb) ? bsum[t] : 0;
    sdata[t] = orig;
    __syncthreads();
    for (int off = 1; off < 256; off <<= 1) {
        int v = (t >= off) ? sdata[t - off] : 0;
        __syncthreads();
        sdata[t] += v;
        __syncthreads();
    }
    if (t < nb) bsum[t] = sdata[t] - orig;  // exclusive
}

// per-block exclusive scan + block offset -> row_ptr
__global__ void k_scanfinal(const int* __restrict__ cnt, const int* __restrict__ bsum_ex,
                            int* __restrict__ row_ptr, int n, int e_total) {
    __shared__ int sdata[256];
    int t = threadIdx.x;
    int i = blockIdx.x * 256 + t;
    int orig = (i < n) ? cnt[i] : 0;
    sdata[t] = orig;
    __syncthreads();
    for (int off = 1; off < 256; off <<= 1) {
        int v = (t >= off) ? sdata[t - off] : 0;
        __syncthreads();
        sdata[t] += v;
        __syncthreads();
    }
    if (i < n) row_ptr[i] = sdata[t] - orig + bsum_ex[blockIdx.x];
    if (i == 0) row_ptr[n] = e_total;
}

__global__ void k_fill(const int* __restrict__ src, const int* __restrict__ dst,
                       const int* __restrict__ row_ptr, int* __restrict__ cur,
                       int* __restrict__ col, int e) {
    int i = blockIdx.x * blockDim.x + threadIdx.x;
    if (i < e) {
        int d = dst[i];
        int pos = atomicAdd(&cur[d], 1);
        col[row_ptr[d] + pos] = src[i];
    }
}

// ---------------- GEMM: Hs = (A @ B) * dinv[row] ----------------
template <int BM, int BN, int BK, int TM, int TN>
__global__ __launch_bounds__((BM / TM) * (BN / TN)) void k_gemm_scale(
    const float* __restrict__ A, const float* __restrict__ B,
    const float* __restrict__ dinv, float* __restrict__ Hs, int M, int K) {
    constexpr int NTH = (BM / TM) * (BN / TN);
    __shared__ float As[BK][BM];
    __shared__ float Bs[BK][BN];

    const int tid = threadIdx.x;
    const int m0 = blockIdx.x * BM;
    const int col_g = tid % (BN / TN);
    const int row_g = tid / (BN / TN);

    float acc[TM][TN];
#pragma unroll
    for (int i = 0; i < TM; ++i)
#pragma unroll
        for (int j = 0; j < TN; ++j) acc[i][j] = 0.0f;

    for (int k0 = 0; k0 < K; k0 += BK) {
#pragma unroll
        for (int idx = tid; idx < BM * BK / 4; idx += NTH) {
            int row = idx / (BK / 4);
            int kq = idx % (BK / 4);
            int gm = m0 + row;
            float4 v = make_float4(0.f, 0.f, 0.f, 0.f);
            if (gm < M) v = *(const float4*)&A[(long)gm * K + k0 + kq * 4];
            As[kq * 4 + 0][row] = v.x;
            As[kq * 4 + 1][row] = v.y;
            As[kq * 4 + 2][row] = v.z;
            As[kq * 4 + 3][row] = v.w;
        }
#pragma unroll
        for (int idx = tid; idx < BK * BN / 4; idx += NTH) {
            int row = idx / (BN / 4);
            int cq = idx % (BN / 4);
            *(float4*)&Bs[row][cq * 4] = *(const float4*)&B[(long)(k0 + row) * BN + cq * 4];
        }
        __syncthreads();

#pragma unroll
        for (int k = 0; k < BK; ++k) {
            float a[TM], b[TN];
            const float4* ap = (const float4*)&As[k][row_g * TM];
#pragma unroll
            for (int i = 0; i < TM / 4; ++i) {
                float4 av = ap[i];
                a[i * 4 + 0] = av.x; a[i * 4 + 1] = av.y;
                a[i * 4 + 2] = av.z; a[i * 4 + 3] = av.w;
            }
            const float4* bp = (const float4*)&Bs[k][col_g * TN];
#pragma unroll
            for (int j = 0; j < TN / 4; ++j) {
                float4 bv = bp[j];
                b[j * 4 + 0] = bv.x; b[j * 4 + 1] = bv.y;
                b[j * 4 + 2] = bv.z; b[j * 4 + 3] = bv.w;
            }
#pragma unroll
            for (int i = 0; i < TM; ++i)
#pragma unroll
                for (int j = 0; j < TN; ++j) acc[i][j] = fmaf(a[i], b[j], acc[i][j]);
        }
        __syncthreads();
    }

#pragma unroll
    for (int i = 0; i < TM; ++i) {
        int gm = m0 + row_g * TM + i;
        if (gm >= M) break;
        float dv = dinv[gm];
#pragma unroll
        for (int j = 0; j < TN / 4; ++j) {
            float4 v;
            v.x = acc[i][j * 4 + 0] * dv;
            v.y = acc[i][j * 4 + 1] * dv;
            v.z = acc[i][j * 4 + 2] * dv;
            v.w = acc[i][j * 4 + 3] * dv;
            *(float4*)&Hs[(long)gm * BN + col_g * TN + j * 4] = v;
        }
    }
}

// ---------------- CSR aggregation, wave per node ----------------
// 128 channels: float2 per lane. z = relu((self + sum_neighbors) * dinv + b)
__global__ __launch_bounds__(256) void k_agg1(
    const float* __restrict__ h, const int* __restrict__ row_ptr,
    const int* __restrict__ col, const float* __restrict__ dinv,
    const float* __restrict__ bias, float* __restrict__ z, int n) {
    int node = blockIdx.x * 4 + (threadIdx.x >> 6);
    node = __builtin_amdgcn_readfirstlane(node);
    if (node >= n) return;
    int lane = threadIdx.x & 63;
    const float2* hp = (const float2*)h;
    float2 acc = hp[(long)node * 64 + lane];  // self-loop
    int rs = row_ptr[node], re = row_ptr[node + 1];
    for (int j = rs; j < re; ++j) {
        int s = col[j];
        float2 v = hp[(long)s * 64 + lane];
        acc.x += v.x;
        acc.y += v.y;
    }
    float dv = dinv[node];
    float2 b = ((const float2*)bias)[lane];
    acc.x = fmaxf(fmaf(acc.x, dv, b.x), 0.f);
    acc.y = fmaxf(fmaf(acc.y, dv, b.y), 0.f);
    ((float2*)z)[(long)node * 64 + lane] = acc;
}

// 64 channels: 1 float per lane, no relu
__global__ __launch_bounds__(256) void k_agg2(
    const float* __restrict__ h, const int* __restrict__ row_ptr,
    const int* __restrict__ col, const float* __restrict__ dinv,
    const float* __restrict__ bias, float* __restrict__ z, int n) {
    int node = blockIdx.x * 4 + (threadIdx.x >> 6);
    node = __builtin_amdgcn_readfirstlane(node);
    if (node >= n) return;
    int lane = threadIdx.x & 63;
    float acc = h[(long)node * 64 + lane];  // self-loop
    int rs = row_ptr[node], re = row_ptr[node + 1];
    for (int j = rs; j < re; ++j) {
        int s = col[j];
        acc += h[(long)s * 64 + lane];
    }
    z[(long)node * 64 + lane] = fmaf(acc, dinv[node], bias[lane]);
}

// ---------------- decoder ----------------
__global__ void k_dot(const float* __restrict__ z2, const int* __restrict__ es,
                      const int* __restrict__ ed, float* __restrict__ out, int L) {
    int gid = blockIdx.x * blockDim.x + threadIdx.x;
    int wid = gid >> 6;
    int lane = threadIdx.x & 63;
    if (wid >= L) return;
    int a = es[wid], b = ed[wid];
    float v = z2[(long)a * OUT_C + lane] * z2[(long)b * OUT_C + lane];
#pragma unroll
    for (int off = 32; off > 0; off >>= 1) v += __shfl_down(v, off);
    if (lane == 0) out[wid] = v;
}

extern "C" void kernel_launch(void* const* d_in, const int* in_sizes, int n_in,
                              void* d_out, int out_size, void* d_ws, size_t ws_size,
                              hipStream_t stream) {
    const float* x = (const float*)d_in[0];
    const int* ei = (const int*)d_in[1];
    const int* eli = (const int*)d_in[2];
    const float* W1 = (const float*)d_in[3];
    const float* b1 = (const float*)d_in[4];
    const float* W2 = (const float*)d_in[5];
    const float* b2 = (const float*)d_in[6];
    float* out = (float*)d_out;

    const int N = in_sizes[0] / IN_C;  // 50000
    const int E = in_sizes[1] / 2;     // 800000
    const int L = in_sizes[2] / 2;     // 100000
    const int* src = ei;
    const int* dst = ei + E;
    const int* es = eli;
    const int* ed = eli + L;

    const int Npad = (N + 63) & ~63;
    const int Epad = (E + 3) & ~3;

    // workspace layout (~55 MB)
    int* cnt = (int*)d_ws;             // Npad
    int* cur = cnt + Npad;             // Npad
    int* row_ptr = cur + Npad;         // Npad + 64  (needs N+1)
    int* bsum = row_ptr + Npad + 64;   // 256
    int* col = bsum + 256;             // Epad
    float* dinv = (float*)(col + Epad);    // Npad
    float* h1s = dinv + Npad;              // N*128
    float* z1 = h1s + (long)N * HID_C;     // N*128
    float* h2s = h1s;                      // alias: h1s dead after agg1
    float* z2 = h1s + (long)N * OUT_C;     // alias: second half of h1s region

    const int TPB = 256;
    const int nb = (N + 255) / 256;  // scan blocks (<=256)

    // CSR build + dinv
    k_zero_int<<<(2 * Npad + TPB - 1) / TPB, TPB, 0, stream>>>(cnt, 2 * Npad);  // cnt+cur
    k_count<<<(E + TPB - 1) / TPB, TPB, 0, stream>>>(dst, cnt, E);
    k_dinv<<<(N + TPB - 1) / TPB, TPB, 0, stream>>>(cnt, dinv, N);
    k_blocksum<<<nb, 256, 0, stream>>>(cnt, bsum, N);
    k_scanpartials<<<1, 256, 0, stream>>>(bsum, nb);
    k_scanfinal<<<nb, 256, 0, stream>>>(cnt, bsum, row_ptr, N, E);
    k_fill<<<(E + TPB - 1) / TPB, TPB, 0, stream>>>(src, dst, row_ptr, cur, col, E);

    // layer 1: h1s = (x @ W1) * dinv[row]; z1 = relu((self+neigh)*dinv + b1)
    k_gemm_scale<64, HID_C, 32, 8, 4>
        <<<(N + 63) / 64, 256, 0, stream>>>(x, W1, dinv, h1s, N, IN_C);
    k_agg1<<<(N + 3) / 4, 256, 0, stream>>>(h1s, row_ptr, col, dinv, b1, z1, N);

    // layer 2 (h2s aliases h1s)
    k_gemm_scale<128, OUT_C, 32, 8, 4>
        <<<(N + 127) / 128, 256, 0, stream>>>(z1, W2, dinv, h2s, N, HID_C);
    k_agg2<<<(N + 3) / 4, 256, 0, stream>>>(h2s, row_ptr, col, dinv, b2, z2, N);

    // decoder
    k_dot<<<((long)L * 64 + TPB - 1) / TPB, TPB, 0, stream>>>(z2, es, ed, out, L);
}

// Round 3
// 456.188 us; speedup vs baseline: 1.8917x; 1.0594x over previous
//
#include <hip/hip_runtime.h>

// GCN 2-layer + edge dot decoder. Dims fixed: in=512, hid=128, out=64.
#define IN_C  512
#define HID_C 128
#define OUT_C 64

using short8 = __attribute__((ext_vector_type(8))) short;   // 8 bf16
using floatx4 = __attribute__((ext_vector_type(4))) float;  // mfma acc

__device__ inline unsigned short f2bf(float f) {  // RNE
    unsigned u = __builtin_bit_cast(unsigned, f);
    u += 0x7FFFu + ((u >> 16) & 1u);
    return (unsigned short)(u >> 16);
}
__device__ inline float bf2f(unsigned short h) {
    unsigned u = ((unsigned)h) << 16;
    return __builtin_bit_cast(float, u);
}

// ---------------- CSR build ----------------
__global__ void k_zero_int(int* __restrict__ p, int n) {
    int i = blockIdx.x * blockDim.x + threadIdx.x;
    if (i < n) p[i] = 0;
}

__global__ void k_count(const int* __restrict__ dst, int* __restrict__ cnt, int e) {
    int i = blockIdx.x * blockDim.x + threadIdx.x;
    if (i < e) atomicAdd(&cnt[dst[i]], 1);
}

__global__ void k_dinv(const int* __restrict__ cnt, float* __restrict__ dinv, int n) {
    int i = blockIdx.x * blockDim.x + threadIdx.x;
    if (i < n) dinv[i] = rsqrtf(1.0f + (float)cnt[i]);  // +1 self-loop
}

__global__ void k_blocksum(const int* __restrict__ cnt, int* __restrict__ bsum, int n) {
    __shared__ int sdata[256];
    int t = threadIdx.x;
    int i = blockIdx.x * 256 + t;
    sdata[t] = (i < n) ? cnt[i] : 0;
    __syncthreads();
    for (int s = 128; s > 0; s >>= 1) {
        if (t < s) sdata[t] += sdata[t + s];
        __syncthreads();
    }
    if (t == 0) bsum[blockIdx.x] = sdata[0];
}

__global__ void k_scanpartials(int* __restrict__ bsum, int nb) {
    __shared__ int sdata[256];
    int t = threadIdx.x;
    int orig = (t < nb) ? bsum[t] : 0;
    sdata[t] = orig;
    __syncthreads();
    for (int off = 1; off < 256; off <<= 1) {
        int v = (t >= off) ? sdata[t - off] : 0;
        __syncthreads();
        sdata[t] += v;
        __syncthreads();
    }
    if (t < nb) bsum[t] = sdata[t] - orig;  // exclusive
}

__global__ void k_scanfinal(const int* __restrict__ cnt, const int* __restrict__ bsum_ex,
                            int* __restrict__ row_ptr, int n, int e_total) {
    __shared__ int sdata[256];
    int t = threadIdx.x;
    int i = blockIdx.x * 256 + t;
    int orig = (i < n) ? cnt[i] : 0;
    sdata[t] = orig;
    __syncthreads();
    for (int off = 1; off < 256; off <<= 1) {
        int v = (t >= off) ? sdata[t - off] : 0;
        __syncthreads();
        sdata[t] += v;
        __syncthreads();
    }
    if (i < n) row_ptr[i] = sdata[t] - orig + bsum_ex[blockIdx.x];
    if (i == 0) row_ptr[n] = e_total;
}

__global__ void k_fill(const int* __restrict__ src, const int* __restrict__ dst,
                       const int* __restrict__ row_ptr, int* __restrict__ cur,
                       int* __restrict__ col, int e) {
    int i = blockIdx.x * blockDim.x + threadIdx.x;
    if (i < e) {
        int d = dst[i];
        int pos = atomicAdd(&cur[d], 1);
        col[row_ptr[d] + pos] = src[i];
    }
}

// ---------------- weight prep: W [K][N] fp32 -> Wt_hi/Wt_lo [N][K] bf16 ----------------
__global__ void k_prep_w(const float* __restrict__ W, unsigned short* __restrict__ hi,
                         unsigned short* __restrict__ lo, int K, int N) {
    int i = blockIdx.x * blockDim.x + threadIdx.x;
    if (i >= K * N) return;
    int k = i / N, n = i % N;
    float v = W[i];
    unsigned short h = f2bf(v);
    float r = v - bf2f(h);
    hi[(long)n * K + k] = h;
    lo[(long)n * K + k] = f2bf(r);
}

// ---------------- split-bf16 MFMA GEMM: Hs = (A @ B) * dinv[row] ----------------
// Block: 256 threads (4 waves). BM=64 rows; wave w covers cols [w*NPW*16, ...).
// N = 64*NPW. A fp32 [M][K] staged per 64-k tile into LDS as bf16 hi/lo.
// B pre-transposed bf16 [N][K] hi/lo, read from global (L1/L2 resident).
template <int K, int NPW>
__global__ __launch_bounds__(256) void k_gemm_mfma(
    const float* __restrict__ A, const unsigned short* __restrict__ Bt_hi,
    const unsigned short* __restrict__ Bt_lo, const float* __restrict__ dinv,
    float* __restrict__ Hs, int M) {
    constexpr int N = 64 * NPW;
    constexpr int LDA = 72;  // 64 + 8 pad: keeps b128 frag reads <=2-way on banks
    __shared__ __align__(16) unsigned short As_hi[64 * LDA];
    __shared__ __align__(16) unsigned short As_lo[64 * LDA];

    const int tid = threadIdx.x;
    const int w = tid >> 6;
    const int lane = tid & 63;
    const int m = lane & 15;
    const int quad = lane >> 4;
    const int m0 = blockIdx.x * 64;

    floatx4 acc[4][NPW];
#pragma unroll
    for (int mi = 0; mi < 4; ++mi)
#pragma unroll
        for (int ni = 0; ni < NPW; ++ni) acc[mi][ni] = (floatx4){0.f, 0.f, 0.f, 0.f};

    for (int k0 = 0; k0 < K; k0 += 64) {
        __syncthreads();
        // stage A 64 rows x 64 k: fp32 -> bf16 hi/lo in LDS
#pragma unroll
        for (int i = 0; i < 4; ++i) {
            int f = i * 256 + tid;
            int row = f >> 4;
            int kk = (f & 15) << 2;
            int gm = m0 + row;
            float4 v = make_float4(0.f, 0.f, 0.f, 0.f);
            if (gm < M) v = *(const float4*)&A[(long)gm * K + k0 + kk];
            ushort4 h, l;
            h.x = f2bf(v.x); l.x = f2bf(v.x - bf2f(h.x));
            h.y = f2bf(v.y); l.y = f2bf(v.y - bf2f(h.y));
            h.z = f2bf(v.z); l.z = f2bf(v.z - bf2f(h.z));
            h.w = f2bf(v.w); l.w = f2bf(v.w - bf2f(h.w));
            *(ushort4*)&As_hi[row * LDA + kk] = h;
            *(ushort4*)&As_lo[row * LDA + kk] = l;
        }
        __syncthreads();

#pragma unroll
        for (int s = 0; s < 2; ++s) {
            short8 ah[4], al[4];
#pragma unroll
            for (int mi = 0; mi < 4; ++mi) {
                int off = (mi * 16 + m) * LDA + s * 32 + quad * 8;
                ah[mi] = *(const short8*)&As_hi[off];
                al[mi] = *(const short8*)&As_lo[off];
            }
#pragma unroll
            for (int ni = 0; ni < NPW; ++ni) {
                int n = (w * NPW + ni) * 16 + m;
                long boff = (long)n * K + k0 + s * 32 + quad * 8;
                short8 bh = *(const short8*)&Bt_hi[boff];
                short8 bl = *(const short8*)&Bt_lo[boff];
#pragma unroll
                for (int mi = 0; mi < 4; ++mi) {
                    acc[mi][ni] = __builtin_amdgcn_mfma_f32_16x16x32_bf16(ah[mi], bh, acc[mi][ni], 0, 0, 0);
                    acc[mi][ni] = __builtin_amdgcn_mfma_f32_16x16x32_bf16(ah[mi], bl, acc[mi][ni], 0, 0, 0);
                    acc[mi][ni] = __builtin_amdgcn_mfma_f32_16x16x32_bf16(al[mi], bh, acc[mi][ni], 0, 0, 0);
                }
            }
        }
    }

    // epilogue: C/D layout col=lane&15, row=quad*4+reg; scale by dinv[row]
#pragma unroll
    for (int mi = 0; mi < 4; ++mi) {
#pragma unroll
        for (int r = 0; r < 4; ++r) {
            int row = m0 + mi * 16 + quad * 4 + r;
            if (row < M) {
                float dv = dinv[row];
#pragma unroll
                for (int ni = 0; ni < NPW; ++ni) {
                    int n = (w * NPW + ni) * 16 + m;
                    Hs[(long)row * N + n] = acc[mi][ni][r] * dv;
                }
            }
        }
    }
}

// ---------------- CSR aggregation, wave per node ----------------
__global__ __launch_bounds__(256) void k_agg1(
    const float* __restrict__ h, const int* __restrict__ row_ptr,
    const int* __restrict__ col, const float* __restrict__ dinv,
    const float* __restrict__ bias, float* __restrict__ z, int n) {
    int node = blockIdx.x * 4 + (threadIdx.x >> 6);
    node = __builtin_amdgcn_readfirstlane(node);
    if (node >= n) return;
    int lane = threadIdx.x & 63;
    const float2* hp = (const float2*)h;
    float2 acc = hp[(long)node * 64 + lane];  // self-loop
    int rs = row_ptr[node], re = row_ptr[node + 1];
    for (int j = rs; j < re; ++j) {
        int s = col[j];
        float2 v = hp[(long)s * 64 + lane];
        acc.x += v.x;
        acc.y += v.y;
    }
    float dv = dinv[node];
    float2 b = ((const float2*)bias)[lane];
    acc.x = fmaxf(fmaf(acc.x, dv, b.x), 0.f);
    acc.y = fmaxf(fmaf(acc.y, dv, b.y), 0.f);
    ((float2*)z)[(long)node * 64 + lane] = acc;
}

__global__ __launch_bounds__(256) void k_agg2(
    const float* __restrict__ h, const int* __restrict__ row_ptr,
    const int* __restrict__ col, const float* __restrict__ dinv,
    const float* __restrict__ bias, float* __restrict__ z, int n) {
    int node = blockIdx.x * 4 + (threadIdx.x >> 6);
    node = __builtin_amdgcn_readfirstlane(node);
    if (node >= n) return;
    int lane = threadIdx.x & 63;
    float acc = h[(long)node * 64 + lane];  // self-loop
    int rs = row_ptr[node], re = row_ptr[node + 1];
    for (int j = rs; j < re; ++j) {
        int s = col[j];
        acc += h[(long)s * 64 + lane];
    }
    z[(long)node * 64 + lane] = fmaf(acc, dinv[node], bias[lane]);
}

// ---------------- decoder ----------------
__global__ void k_dot(const float* __restrict__ z2, const int* __restrict__ es,
                      const int* __restrict__ ed, float* __restrict__ out, int L) {
    int gid = blockIdx.x * blockDim.x + threadIdx.x;
    int wid = gid >> 6;
    int lane = threadIdx.x & 63;
    if (wid >= L) return;
    int a = es[wid], b = ed[wid];
    float v = z2[(long)a * OUT_C + lane] * z2[(long)b * OUT_C + lane];
#pragma unroll
    for (int off = 32; off > 0; off >>= 1) v += __shfl_down(v, off);
    if (lane == 0) out[wid] = v;
}

extern "C" void kernel_launch(void* const* d_in, const int* in_sizes, int n_in,
                              void* d_out, int out_size, void* d_ws, size_t ws_size,
                              hipStream_t stream) {
    const float* x = (const float*)d_in[0];
    const int* ei = (const int*)d_in[1];
    const int* eli = (const int*)d_in[2];
    const float* W1 = (const float*)d_in[3];
    const float* b1 = (const float*)d_in[4];
    const float* W2 = (const float*)d_in[5];
    const float* b2 = (const float*)d_in[6];
    float* out = (float*)d_out;

    const int N = in_sizes[0] / IN_C;  // 50000
    const int E = in_sizes[1] / 2;     // 800000
    const int L = in_sizes[2] / 2;     // 100000
    const int* src = ei;
    const int* dst = ei + E;
    const int* es = eli;
    const int* ed = eli + L;

    const int Npad = (N + 63) & ~63;
    const int Epad = (E + 3) & ~3;

    // workspace layout (~56 MB; harness provides >= 77 MB per round-1 run)
    int* cnt = (int*)d_ws;             // Npad
    int* cur = cnt + Npad;             // Npad
    int* row_ptr = cur + Npad;         // Npad + 64
    int* bsum = row_ptr + Npad + 64;   // 256
    int* col = bsum + 256;             // Epad
    float* dinv = (float*)(col + Epad);    // Npad
    float* h1s = dinv + Npad;              // N*128
    float* z1 = h1s + (long)N * HID_C;     // N*128
    float* h2s = h1s;                      // alias: h1s dead after agg1
    float* z2 = h1s + (long)N * OUT_C;     // alias: disjoint from h2s
    unsigned short* wt1_hi = (unsigned short*)(z1 + (long)N * HID_C);  // 512*128
    unsigned short* wt1_lo = wt1_hi + IN_C * HID_C;
    unsigned short* wt2_hi = wt1_lo + IN_C * HID_C;                    // 128*64
    unsigned short* wt2_lo = wt2_hi + HID_C * OUT_C;

    const int TPB = 256;
    const int nb = (N + 255) / 256;

    // weight prep (independent of graph)
    k_prep_w<<<(IN_C * HID_C + TPB - 1) / TPB, TPB, 0, stream>>>(W1, wt1_hi, wt1_lo, IN_C, HID_C);
    k_prep_w<<<(HID_C * OUT_C + TPB - 1) / TPB, TPB, 0, stream>>>(W2, wt2_hi, wt2_lo, HID_C, OUT_C);

    // CSR build + dinv
    k_zero_int<<<(2 * Npad + TPB - 1) / TPB, TPB, 0, stream>>>(cnt, 2 * Npad);
    k_count<<<(E + TPB - 1) / TPB, TPB, 0, stream>>>(dst, cnt, E);
    k_dinv<<<(N + TPB - 1) / TPB, TPB, 0, stream>>>(cnt, dinv, N);
    k_blocksum<<<nb, 256, 0, stream>>>(cnt, bsum, N);
    k_scanpartials<<<1, 256, 0, stream>>>(bsum, nb);
    k_scanfinal<<<nb, 256, 0, stream>>>(cnt, bsum, row_ptr, N, E);
    k_fill<<<(E + TPB - 1) / TPB, TPB, 0, stream>>>(src, dst, row_ptr, cur, col, E);

    // layer 1
    k_gemm_mfma<IN_C, 2><<<(N + 63) / 64, 256, 0, stream>>>(x, wt1_hi, wt1_lo, dinv, h1s, N);
    k_agg1<<<(N + 3) / 4, 256, 0, stream>>>(h1s, row_ptr, col, dinv, b1, z1, N);

    // layer 2
    k_gemm_mfma<HID_C, 1><<<(N + 63) / 64, 256, 0, stream>>>(z1, wt2_hi, wt2_lo, dinv, h2s, N);
    k_agg2<<<(N + 3) / 4, 256, 0, stream>>>(h2s, row_ptr, col, dinv, b2, z2, N);

    // decoder
    k_dot<<<((long)L * 64 + TPB - 1) / TPB, TPB, 0, stream>>>(z2, es, ed, out, L);
}

// Round 4
// 405.600 us; speedup vs baseline: 2.1276x; 1.1247x over previous
//
#include <hip/hip_runtime.h>

// GCN 2-layer + edge dot decoder. Dims fixed: in=512, hid=128, out=64.
#define IN_C  512
#define HID_C 128
#define OUT_C 64

using short8 = __attribute__((ext_vector_type(8))) short;   // 8 bf16
using floatx4 = __attribute__((ext_vector_type(4))) float;  // mfma acc

__device__ inline unsigned short f2bf(float f) {  // RNE
    unsigned u = __builtin_bit_cast(unsigned, f);
    u += 0x7FFFu + ((u >> 16) & 1u);
    return (unsigned short)(u >> 16);
}
__device__ inline float bf2f(unsigned short h) {
    unsigned u = ((unsigned)h) << 16;
    return __builtin_bit_cast(float, u);
}

// ---------------- CSR build ----------------
__global__ void k_zero_int(int* __restrict__ p, int n) {
    int i = blockIdx.x * blockDim.x + threadIdx.x;
    if (i < n) p[i] = 0;
}

__global__ void k_count(const int* __restrict__ dst, int* __restrict__ cnt, int e) {
    int i = blockIdx.x * blockDim.x + threadIdx.x;
    if (i < e) atomicAdd(&cnt[dst[i]], 1);
}

__global__ void k_dinv(const int* __restrict__ cnt, float* __restrict__ dinv, int n) {
    int i = blockIdx.x * blockDim.x + threadIdx.x;
    if (i < n) dinv[i] = rsqrtf(1.0f + (float)cnt[i]);  // +1 self-loop
}

__global__ void k_blocksum(const int* __restrict__ cnt, int* __restrict__ bsum, int n) {
    __shared__ int sdata[256];
    int t = threadIdx.x;
    int i = blockIdx.x * 256 + t;
    sdata[t] = (i < n) ? cnt[i] : 0;
    __syncthreads();
    for (int s = 128; s > 0; s >>= 1) {
        if (t < s) sdata[t] += sdata[t + s];
        __syncthreads();
    }
    if (t == 0) bsum[blockIdx.x] = sdata[0];
}

__global__ void k_scanpartials(int* __restrict__ bsum, int nb) {
    __shared__ int sdata[256];
    int t = threadIdx.x;
    int orig = (t < nb) ? bsum[t] : 0;
    sdata[t] = orig;
    __syncthreads();
    for (int off = 1; off < 256; off <<= 1) {
        int v = (t >= off) ? sdata[t - off] : 0;
        __syncthreads();
        sdata[t] += v;
        __syncthreads();
    }
    if (t < nb) bsum[t] = sdata[t] - orig;  // exclusive
}

__global__ void k_scanfinal(const int* __restrict__ cnt, const int* __restrict__ bsum_ex,
                            int* __restrict__ row_ptr, int n, int e_total) {
    __shared__ int sdata[256];
    int t = threadIdx.x;
    int i = blockIdx.x * 256 + t;
    int orig = (i < n) ? cnt[i] : 0;
    sdata[t] = orig;
    __syncthreads();
    for (int off = 1; off < 256; off <<= 1) {
        int v = (t >= off) ? sdata[t - off] : 0;
        __syncthreads();
        sdata[t] += v;
        __syncthreads();
    }
    if (i < n) row_ptr[i] = sdata[t] - orig + bsum_ex[blockIdx.x];
    if (i == 0) row_ptr[n] = e_total;
}

__global__ void k_fill(const int* __restrict__ src, const int* __restrict__ dst,
                       const int* __restrict__ row_ptr, int* __restrict__ cur,
                       int* __restrict__ col, int e) {
    int i = blockIdx.x * blockDim.x + threadIdx.x;
    if (i < e) {
        int d = dst[i];
        int pos = atomicAdd(&cur[d], 1);
        col[row_ptr[d] + pos] = src[i];
    }
}

// ---------------- weight prep: W [K][N] fp32 -> Wt_hi/Wt_lo [N][K] bf16 ----------------
__global__ void k_prep_w(const float* __restrict__ W, unsigned short* __restrict__ hi,
                         unsigned short* __restrict__ lo, int K, int N) {
    int i = blockIdx.x * blockDim.x + threadIdx.x;
    if (i >= K * N) return;
    int k = i / N, n = i % N;
    float v = W[i];
    unsigned short h = f2bf(v);
    float r = v - bf2f(h);
    hi[(long)n * K + k] = h;
    lo[(long)n * K + k] = f2bf(r);
}

// ---------------- split-bf16 MFMA GEMM, register-prefetch double-buffered ----------------
// Block 256 (4 waves), BM=64 rows, N = 64*NPW cols. One barrier per 64-k tile:
//   barrier -> issue loads(t+1) -> compute buf[t&1] -> convert regs -> buf[(t+1)&1]
// Safety: a wave writes buf[(t+1)&1] only after passing barrier t; any wave still
// reading that buffer (iter t+1) can't be past barrier t+1, which needs our arrival.
template <int K, int NPW>
__global__ __launch_bounds__(256) void k_gemm_mfma(
    const float* __restrict__ A, const unsigned short* __restrict__ Bt_hi,
    const unsigned short* __restrict__ Bt_lo, const float* __restrict__ dinv,
    float* __restrict__ Hs, int M) {
    constexpr int N = 64 * NPW;
    constexpr int LDA = 72;       // shorts; 144 B rows: frag b128 reads land 2-way (free)
    constexpr int NT = K / 64;    // number of 64-k tiles
    __shared__ __align__(16) unsigned short As_hi[2][64 * LDA];
    __shared__ __align__(16) unsigned short As_lo[2][64 * LDA];

    const int tid = threadIdx.x;
    const int w = tid >> 6;
    const int lane = tid & 63;
    const int m = lane & 15;
    const int quad = lane >> 4;
    const int m0 = blockIdx.x * 64;

    // staging coords: thread handles rows srow+16i, fixed 4-float column skk
    const int srow = tid >> 4;
    const int skk = (tid & 15) << 2;

    floatx4 acc[4][NPW];
#pragma unroll
    for (int mi = 0; mi < 4; ++mi)
#pragma unroll
        for (int ni = 0; ni < NPW; ++ni) acc[mi][ni] = (floatx4){0.f, 0.f, 0.f, 0.f};

    float4 pf[4];
    // prologue: load + convert tile 0 into buf 0
#pragma unroll
    for (int i = 0; i < 4; ++i) {
        int gm = m0 + srow + 16 * i;
        pf[i] = make_float4(0.f, 0.f, 0.f, 0.f);
        if (gm < M) pf[i] = *(const float4*)&A[(long)gm * K + skk];
    }
#pragma unroll
    for (int i = 0; i < 4; ++i) {
        ushort4 h, l;
        h.x = f2bf(pf[i].x); l.x = f2bf(pf[i].x - bf2f(h.x));
        h.y = f2bf(pf[i].y); l.y = f2bf(pf[i].y - bf2f(h.y));
        h.z = f2bf(pf[i].z); l.z = f2bf(pf[i].z - bf2f(h.z));
        h.w = f2bf(pf[i].w); l.w = f2bf(pf[i].w - bf2f(h.w));
        int off = (srow + 16 * i) * LDA + skk;
        *(ushort4*)&As_hi[0][off] = h;
        *(ushort4*)&As_lo[0][off] = l;
    }

    for (int t = 0; t < NT; ++t) {
        __syncthreads();  // buf[t&1] fully written; prior readers of buf[(t+1)&1] done
        const int buf = t & 1;
        // prefetch next tile into registers (latency overlaps compute below)
        if (t + 1 < NT) {
#pragma unroll
            for (int i = 0; i < 4; ++i) {
                int gm = m0 + srow + 16 * i;
                pf[i] = make_float4(0.f, 0.f, 0.f, 0.f);
                if (gm < M) pf[i] = *(const float4*)&A[(long)gm * K + (t + 1) * 64 + skk];
            }
        }
        // compute from buf
#pragma unroll
        for (int s = 0; s < 2; ++s) {
            short8 ah[4], al[4];
#pragma unroll
            for (int mi = 0; mi < 4; ++mi) {
                int off = (mi * 16 + m) * LDA + s * 32 + quad * 8;
                ah[mi] = *(const short8*)&As_hi[buf][off];
                al[mi] = *(const short8*)&As_lo[buf][off];
            }
#pragma unroll
            for (int ni = 0; ni < NPW; ++ni) {
                int n = (w * NPW + ni) * 16 + m;
                long boff = (long)n * K + t * 64 + s * 32 + quad * 8;
                short8 bh = *(const short8*)&Bt_hi[boff];
                short8 bl = *(const short8*)&Bt_lo[boff];
#pragma unroll
                for (int mi = 0; mi < 4; ++mi) {
                    acc[mi][ni] = __builtin_amdgcn_mfma_f32_16x16x32_bf16(ah[mi], bh, acc[mi][ni], 0, 0, 0);
                    acc[mi][ni] = __builtin_amdgcn_mfma_f32_16x16x32_bf16(ah[mi], bl, acc[mi][ni], 0, 0, 0);
                    acc[mi][ni] = __builtin_amdgcn_mfma_f32_16x16x32_bf16(al[mi], bh, acc[mi][ni], 0, 0, 0);
                }
            }
        }
        // convert prefetched regs into the other buffer
        if (t + 1 < NT) {
#pragma unroll
            for (int i = 0; i < 4; ++i) {
                ushort4 h, l;
                h.x = f2bf(pf[i].x); l.x = f2bf(pf[i].x - bf2f(h.x));
                h.y = f2bf(pf[i].y); l.y = f2bf(pf[i].y - bf2f(h.y));
                h.z = f2bf(pf[i].z); l.z = f2bf(pf[i].z - bf2f(h.z));
                h.w = f2bf(pf[i].w); l.w = f2bf(pf[i].w - bf2f(h.w));
                int off = (srow + 16 * i) * LDA + skk;
                *(ushort4*)&As_hi[buf ^ 1][off] = h;
                *(ushort4*)&As_lo[buf ^ 1][off] = l;
            }
        }
    }

    // epilogue: C/D layout col=lane&15, row=quad*4+reg; scale by dinv[row]
#pragma unroll
    for (int mi = 0; mi < 4; ++mi) {
#pragma unroll
        for (int r = 0; r < 4; ++r) {
            int row = m0 + mi * 16 + quad * 4 + r;
            if (row < M) {
                float dv = dinv[row];
#pragma unroll
                for (int ni = 0; ni < NPW; ++ni) {
                    int n = (w * NPW + ni) * 16 + m;
                    Hs[(long)row * N + n] = acc[mi][ni][r] * dv;
                }
            }
        }
    }
}

// ---------------- CSR aggregation, wave per node, 4x unrolled gathers ----------------
__global__ __launch_bounds__(256) void k_agg1(
    const float* __restrict__ h, const int* __restrict__ row_ptr,
    const int* __restrict__ col, const float* __restrict__ dinv,
    const float* __restrict__ bias, float* __restrict__ z, int n) {
    int node = blockIdx.x * 4 + (threadIdx.x >> 6);
    node = __builtin_amdgcn_readfirstlane(node);
    if (node >= n) return;
    int lane = threadIdx.x & 63;
    const float2* hp = (const float2*)h;
    float2 acc = hp[(long)node * 64 + lane];  // self-loop
    int rs = row_ptr[node], re = row_ptr[node + 1];
    int j = rs;
    for (; j + 4 <= re; j += 4) {
        int s0 = col[j], s1 = col[j + 1], s2 = col[j + 2], s3 = col[j + 3];
        float2 v0 = hp[(long)s0 * 64 + lane];
        float2 v1 = hp[(long)s1 * 64 + lane];
        float2 v2 = hp[(long)s2 * 64 + lane];
        float2 v3 = hp[(long)s3 * 64 + lane];
        acc.x += v0.x + v1.x + v2.x + v3.x;
        acc.y += v0.y + v1.y + v2.y + v3.y;
    }
    for (; j < re; ++j) {
        int s = col[j];
        float2 v = hp[(long)s * 64 + lane];
        acc.x += v.x;
        acc.y += v.y;
    }
    float dv = dinv[node];
    float2 b = ((const float2*)bias)[lane];
    acc.x = fmaxf(fmaf(acc.x, dv, b.x), 0.f);
    acc.y = fmaxf(fmaf(acc.y, dv, b.y), 0.f);
    ((float2*)z)[(long)node * 64 + lane] = acc;
}

__global__ __launch_bounds__(256) void k_agg2(
    const float* __restrict__ h, const int* __restrict__ row_ptr,
    const int* __restrict__ col, const float* __restrict__ dinv,
    const float* __restrict__ bias, float* __restrict__ z, int n) {
    int node = blockIdx.x * 4 + (threadIdx.x >> 6);
    node = __builtin_amdgcn_readfirstlane(node);
    if (node >= n) return;
    int lane = threadIdx.x & 63;
    float acc = h[(long)node * 64 + lane];  // self-loop
    int rs = row_ptr[node], re = row_ptr[node + 1];
    int j = rs;
    for (; j + 4 <= re; j += 4) {
        int s0 = col[j], s1 = col[j + 1], s2 = col[j + 2], s3 = col[j + 3];
        acc += h[(long)s0 * 64 + lane] + h[(long)s1 * 64 + lane] +
               h[(long)s2 * 64 + lane] + h[(long)s3 * 64 + lane];
    }
    for (; j < re; ++j) acc += h[(long)col[j] * 64 + lane];
    z[(long)node * 64 + lane] = fmaf(acc, dinv[node], bias[lane]);
}

// ---------------- decoder ----------------
__global__ void k_dot(const float* __restrict__ z2, const int* __restrict__ es,
                      const int* __restrict__ ed, float* __restrict__ out, int L) {
    int gid = blockIdx.x * blockDim.x + threadIdx.x;
    int wid = gid >> 6;
    int lane = threadIdx.x & 63;
    if (wid >= L) return;
    int a = es[wid], b = ed[wid];
    float v = z2[(long)a * OUT_C + lane] * z2[(long)b * OUT_C + lane];
#pragma unroll
    for (int off = 32; off > 0; off >>= 1) v += __shfl_down(v, off);
    if (lane == 0) out[wid] = v;
}

extern "C" void kernel_launch(void* const* d_in, const int* in_sizes, int n_in,
                              void* d_out, int out_size, void* d_ws, size_t ws_size,
                              hipStream_t stream) {
    const float* x = (const float*)d_in[0];
    const int* ei = (const int*)d_in[1];
    const int* eli = (const int*)d_in[2];
    const float* W1 = (const float*)d_in[3];
    const float* b1 = (const float*)d_in[4];
    const float* W2 = (const float*)d_in[5];
    const float* b2 = (const float*)d_in[6];
    float* out = (float*)d_out;

    const int N = in_sizes[0] / IN_C;  // 50000
    const int E = in_sizes[1] / 2;     // 800000
    const int L = in_sizes[2] / 2;     // 100000
    const int* src = ei;
    const int* dst = ei + E;
    const int* es = eli;
    const int* ed = eli + L;

    const int Npad = (N + 63) & ~63;
    const int Epad = (E + 3) & ~3;

    // workspace layout (~56 MB)
    int* cnt = (int*)d_ws;             // Npad
    int* cur = cnt + Npad;             // Npad
    int* row_ptr = cur + Npad;         // Npad + 64
    int* bsum = row_ptr + Npad + 64;   // 256
    int* col = bsum + 256;             // Epad
    float* dinv = (float*)(col + Epad);    // Npad
    float* h1s = dinv + Npad;              // N*128
    float* z1 = h1s + (long)N * HID_C;     // N*128
    float* h2s = h1s;                      // alias: h1s dead after agg1
    float* z2 = h1s + (long)N * OUT_C;     // alias: disjoint from h2s
    unsigned short* wt1_hi = (unsigned short*)(z1 + (long)N * HID_C);  // 512*128
    unsigned short* wt1_lo = wt1_hi + IN_C * HID_C;
    unsigned short* wt2_hi = wt1_lo + IN_C * HID_C;                    // 128*64
    unsigned short* wt2_lo = wt2_hi + HID_C * OUT_C;

    const int TPB = 256;
    const int nb = (N + 255) / 256;

    // weight prep
    k_prep_w<<<(IN_C * HID_C + TPB - 1) / TPB, TPB, 0, stream>>>(W1, wt1_hi, wt1_lo, IN_C, HID_C);
    k_prep_w<<<(HID_C * OUT_C + TPB - 1) / TPB, TPB, 0, stream>>>(W2, wt2_hi, wt2_lo, HID_C, OUT_C);

    // CSR build + dinv
    k_zero_int<<<(2 * Npad + TPB - 1) / TPB, TPB, 0, stream>>>(cnt, 2 * Npad);
    k_count<<<(E + TPB - 1) / TPB, TPB, 0, stream>>>(dst, cnt, E);
    k_dinv<<<(N + TPB - 1) / TPB, TPB, 0, stream>>>(cnt, dinv, N);
    k_blocksum<<<nb, 256, 0, stream>>>(cnt, bsum, N);
    k_scanpartials<<<1, 256, 0, stream>>>(bsum, nb);
    k_scanfinal<<<nb, 256, 0, stream>>>(cnt, bsum, row_ptr, N, E);
    k_fill<<<(E + TPB - 1) / TPB, TPB, 0, stream>>>(src, dst, row_ptr, cur, col, E);

    // layer 1
    k_gemm_mfma<IN_C, 2><<<(N + 63) / 64, 256, 0, stream>>>(x, wt1_hi, wt1_lo, dinv, h1s, N);
    k_agg1<<<(N + 3) / 4, 256, 0, stream>>>(h1s, row_ptr, col, dinv, b1, z1, N);

    // layer 2
    k_gemm_mfma<HID_C, 1><<<(N + 63) / 64, 256, 0, stream>>>(z1, wt2_hi, wt2_lo, dinv, h2s, N);
    k_agg2<<<(N + 3) / 4, 256, 0, stream>>>(h2s, row_ptr, col, dinv, b2, z2, N);

    // decoder
    k_dot<<<((long)L * 64 + TPB - 1) / TPB, TPB, 0, stream>>>(z2, es, ed, out, L);
}